// Round 17
// baseline (408.741 us; speedup 1.0000x reference)
//
#include <hip/hip_runtime.h>
#include <hip/hip_bf16.h>
#include <stdint.h>

// B=1, S=2048, D=4096, H=32, HD=128
// Pipeline: prep(x/wq/wk/wv casts + rope table) -> qkv_proj (QK 256^2 w/ fused RoPE+scale,
//           bm-fastest L2 affinity; V 128x256 w/ fused transpose -> vt) -> attn split-K
//           (exp2 softmax, setprio, + hidden wo cast) -> combine (bq>=16) -> out GEMM
//           (bm-fastest L2 affinity)

typedef __attribute__((ext_vector_type(8))) short bf16x8;
typedef __attribute__((ext_vector_type(4))) float f32x4;

#define S_LEN 2048
#define DMODEL 4096
#define NHEAD 32
#define HDIM 128
#define QKV_LD 12288  // row stride of qk output buffer (Q 0..4095, K 4096..8191)

// Q pre-scale: 1/sqrt(128) * log2(e)  (folded so attn softmax uses native exp2)
#define QSCALE 0.1275247584969759f

// ---------------- helpers ----------------
__device__ __forceinline__ unsigned short f2bf(float f) {
  unsigned int u = __float_as_uint(f);
  unsigned int r = u + 0x7FFFu + ((u >> 16) & 1u);  // RNE
  return (unsigned short)(r >> 16);
}
__device__ __forceinline__ float bf2f(unsigned short h) {
  return __uint_as_float(((unsigned int)h) << 16);
}
__device__ __forceinline__ void gl_lds16(const void* g, void* l) {
  __builtin_amdgcn_global_load_lds((const __attribute__((address_space(1))) unsigned int*)g,
                                   (__attribute__((address_space(3))) unsigned int*)l, 16, 0, 0);
}
__device__ __forceinline__ void phase_barrier() {
  __builtin_amdgcn_sched_barrier(0);
  asm volatile("" ::: "memory");
  __builtin_amdgcn_s_barrier();
  asm volatile("" ::: "memory");
  __builtin_amdgcn_sched_barrier(0);
}
__device__ __forceinline__ void wait_vmcnt6() {
  __builtin_amdgcn_sched_barrier(0);
  asm volatile("s_waitcnt vmcnt(6)" ::: "memory");
  __builtin_amdgcn_sched_barrier(0);
}
__device__ __forceinline__ void wait_vmcnt4() {
  __builtin_amdgcn_sched_barrier(0);
  asm volatile("s_waitcnt vmcnt(4)" ::: "memory");
  __builtin_amdgcn_sched_barrier(0);
}

// ---------------- merged prep: x/wq/wk/wv casts + rope cos/sin table ----------------
__device__ __forceinline__ void cvt4(const float* __restrict__ s, unsigned short* __restrict__ d,
                                     int i) {
  float4 v = ((const float4*)s)[i];
  ushort4 o;
  o.x = f2bf(v.x); o.y = f2bf(v.y); o.z = f2bf(v.z); o.w = f2bf(v.w);
  ((ushort4*)d)[i] = o;
}

__global__ __launch_bounds__(256) void prep_inputs(const float* __restrict__ x,
                                                   const float* __restrict__ wq,
                                                   const float* __restrict__ wk,
                                                   const float* __restrict__ wv,
                                                   const float* __restrict__ fr,
                                                   unsigned short* __restrict__ xb,
                                                   unsigned short* __restrict__ wqkvb,
                                                   float* __restrict__ cs) {
  const int NX = 2097152;   // x float4 count
  const int NW = 4194304;   // each weight float4 count
  const int NR = S_LEN * 64;
  const int total = NX + 3 * NW + NR;
  int i = blockIdx.x * blockDim.x + threadIdx.x;
  int stride = gridDim.x * blockDim.x;
  for (; i < total; i += stride) {
    if (i < NX) {
      cvt4(x, xb, i);
    } else if (i < NX + NW) {
      cvt4(wq, wqkvb, i - NX);
    } else if (i < NX + 2 * NW) {
      cvt4(wk, wqkvb + 16777216, i - NX - NW);
    } else if (i < NX + 3 * NW) {
      cvt4(wv, wqkvb + 33554432, i - NX - 2 * NW);
    } else {
      int j = i - (NX + 3 * NW);
      float f = fr[j];
      cs[2 * j]     = cosf(f);
      cs[2 * j + 1] = sinf(f);
    }
  }
}

// ---------------- shared GEMM building blocks ----------------
__device__ __forceinline__ void mfma_quad(f32x4 (&acc)[8][4], const bf16x8 (&af)[4][2],
                                          const bf16x8 (&bf)[2][2], int moff, int noff) {
  __builtin_amdgcn_s_setprio(1);
#pragma unroll
  for (int mi = 0; mi < 4; ++mi)
#pragma unroll
    for (int ni = 0; ni < 2; ++ni)
#pragma unroll
      for (int kk = 0; kk < 2; ++kk)
        acc[moff + mi][noff + ni] = __builtin_amdgcn_mfma_f32_16x16x32_bf16(
            af[mi][kk], bf[ni][kk], acc[moff + mi][noff + ni], 0, 0, 0);
  __builtin_amdgcn_s_setprio(0);
}
__device__ __forceinline__ void mfma_quad2(f32x4 (&acc)[4][4], const bf16x8 (&af)[2][2],
                                           const bf16x8 (&bf)[2][2], int moff, int noff) {
  __builtin_amdgcn_s_setprio(1);
#pragma unroll
  for (int mi = 0; mi < 2; ++mi)
#pragma unroll
    for (int ni = 0; ni < 2; ++ni)
#pragma unroll
      for (int kk = 0; kk < 2; ++kk)
        acc[moff + mi][noff + ni] = __builtin_amdgcn_mfma_f32_16x16x32_bf16(
            af[mi][kk], bf[ni][kk], acc[moff + mi][noff + ni], 0, 0, 0);
  __builtin_amdgcn_s_setprio(0);
}

__device__ __forceinline__ void read_a(bf16x8 (&dst)[4][2], const char* base, int half,
                                       int wr, int l15, int l4, int swz) {
#pragma unroll
  for (int mi = 0; mi < 4; ++mi) {
    const char* rb = base + (wr * 128 + half * 64 + mi * 16 + l15) * 128;
#pragma unroll
    for (int kk = 0; kk < 2; ++kk)
      dst[mi][kk] = *(const bf16x8*)(rb + ((kk * 64 + l4 * 16) ^ swz));
  }
}
__device__ __forceinline__ void read_b(bf16x8 (&dst)[2][2], const char* base, int half,
                                       int wc, int l15, int l4, int swz) {
#pragma unroll
  for (int ni = 0; ni < 2; ++ni) {
    const char* rb = base + (wc * 64 + half * 32 + ni * 16 + l15) * 128;
#pragma unroll
    for (int kk = 0; kk < 2; ++kk)
      dst[ni][kk] = *(const bf16x8*)(rb + ((kk * 64 + l4 * 16) ^ swz));
  }
}
__device__ __forceinline__ void read_a2(bf16x8 (&dst)[2][2], const char* base, int half,
                                        int wr, int l15, int l4, int swz) {
#pragma unroll
  for (int mi = 0; mi < 2; ++mi) {
    const char* rb = base + (wr * 64 + half * 32 + mi * 16 + l15) * 128;
#pragma unroll
    for (int kk = 0; kk < 2; ++kk)
      dst[mi][kk] = *(const bf16x8*)(rb + ((kk * 64 + l4 * 16) ^ swz));
  }
}
__device__ __forceinline__ void read_b2(bf16x8 (&dst)[2][2], const char* base, int half,
                                        int wc, int l15, int l4, int swz) {
#pragma unroll
  for (int ni = 0; ni < 2; ++ni) {
    const char* rb = base + (wc * 64 + half * 32 + ni * 16 + l15) * 128;
#pragma unroll
    for (int kk = 0; kk < 2; ++kk)
      dst[ni][kk] = *(const bf16x8*)(rb + ((kk * 64 + l4 * 16) ^ swz));
  }
}

// ---------------- 256^2 8-phase GEMM body, register-pipelined; fused RoPE + Q-scale ----------------
template <bool OUT_BF16, bool ROPE>
__device__ __forceinline__ void gemm256_body(const unsigned short* __restrict__ A,
                                             const unsigned short* __restrict__ B,
                                             void* __restrict__ C,
                                             int M, int N, int K, int ldc,
                                             char* smem, int bm, int bn,
                                             const float* __restrict__ cs) {
  const int tid = threadIdx.x;
  const int lane = tid & 63, wid = tid >> 6;
  const int wr = wid >> 2, wc = wid & 3;
  const int l15 = lane & 15, l4 = lane >> 4;

  const int nk = K >> 6;

  unsigned short* AlB = (unsigned short*)smem;          // 2 x 16384 elems (64 KiB)
  unsigned short* BlB = (unsigned short*)smem + 32768;  // 2 x 16384 elems (64 KiB)

  const int srow = tid >> 3;
  const int scol = ((tid & 7) ^ (srow & 7)) * 8;
  const unsigned short* Asrc = A + (size_t)(bm * 256 + srow) * K + scol;
  const unsigned short* Bsrc = B + (size_t)(bn * 256 + srow) * K + scol;
  const int ldsdst = wid * 512;

#define STA(b, kt, q) gl_lds16(Asrc + ((size_t)(q) * 64) * K + (kt) * 64, AlB + (b) * 16384 + (q) * 4096 + ldsdst)
#define STB(b, kt, q) gl_lds16(Bsrc + ((size_t)(q) * 64) * K + (kt) * 64, BlB + (b) * 16384 + (q) * 4096 + ldsdst)

  const int swz = (l15 & 7) << 4;

  f32x4 acc[8][4] = {};
  bf16x8 Ax[4][2], Ay[4][2], B0f[2][2], B1f[2][2];

#pragma unroll
  for (int q = 0; q < 4; ++q) STA(0, 0, q);
#pragma unroll
  for (int q = 0; q < 4; ++q) STB(0, 0, q);
  {
    const int k1 = (nk > 1) ? 1 : 0;
    STA(1, k1, 0); STA(1, k1, 2);
    STB(1, k1, 0); STB(1, k1, 1); STB(1, k1, 2); STB(1, k1, 3);
  }
  wait_vmcnt6();
  phase_barrier();
  read_a(Ax, (const char*)AlB, 0, wr, l15, l4, swz);
  read_b(B0f, (const char*)BlB, 0, wc, l15, l4, swz);

#define HALF(bb, AC, AA, t)                                                \
  {                                                                        \
    const int kt1 = ((t) + 1 < nk) ? (t) + 1 : nk - 1;                     \
    const int kt2 = ((t) + 2 < nk) ? (t) + 2 : nk - 1;                     \
    const char* Ab = (const char*)(AlB + (bb) * 16384);                    \
    const char* Bb = (const char*)(BlB + (bb) * 16384);                    \
    const char* Abn = (const char*)(AlB + ((bb) ^ 1) * 16384);             \
    const char* Bbn = (const char*)(BlB + ((bb) ^ 1) * 16384);             \
    STA((bb) ^ 1, kt1, 1); STA((bb) ^ 1, kt1, 3);                          \
    phase_barrier();                                                       \
    mfma_quad(acc, AC, B0f, 0, 0); /* Q1 */                                \
    read_a(AA, Ab, 1, wr, l15, l4, swz);                                   \
    STA(bb, kt2, 0); STA(bb, kt2, 2);                                      \
    phase_barrier();                                                       \
    mfma_quad(acc, AA, B0f, 4, 0); /* Q2 */                                \
    read_b(B1f, Bb, 1, wc, l15, l4, swz);                                  \
    STB(bb, kt2, 0); STB(bb, kt2, 1);                                      \
    phase_barrier();                                                       \
    mfma_quad(acc, AA, B1f, 4, 2); /* Q3 */                                \
    STB(bb, kt2, 2); STB(bb, kt2, 3);                                      \
    wait_vmcnt6();                                                         \
    phase_barrier();                                                       \
    mfma_quad(acc, AC, B1f, 0, 2); /* Q4 */                                \
    read_a(AA, Abn, 0, wr, l15, l4, swz);                                  \
    read_b(B0f, Bbn, 0, wc, l15, l4, swz);                                 \
  }

  for (int t = 0; t < nk; t += 2) {
    HALF(0, Ax, Ay, t);
    HALF(1, Ay, Ax, t + 1);
  }
#undef HALF
#undef STA
#undef STB

  __builtin_amdgcn_sched_barrier(0);
  asm volatile("s_waitcnt vmcnt(0)" ::: "memory");

  const size_t crow0 = (size_t)bm * 256 + wr * 128 + l4 * 4;
  const int ccol0 = bn * 256 + wc * 64 + l15;
#pragma unroll
  for (int mf = 0; mf < 8; ++mf)
#pragma unroll
    for (int nf = 0; nf < 4; ++nf) {
      size_t row = crow0 + mf * 16;
      int col = ccol0 + nf * 16;
      if (ROPE) {
        const int d = col & (HDIM - 1);
        const int i2 = d & ~1;
        const float fs = (col < 4096) ? QSCALE : 1.0f;
        unsigned short* Cp = (unsigned short*)C;
#pragma unroll
        for (int r = 0; r < 4; ++r) {
          float v = acc[mf][nf][r];
          float vp = __shfl_xor(v, 1, 64);
          float2 csv = *(const float2*)&cs[(row + r) * HDIM + i2];
          float o = ((d & 1) == 0) ? (v * csv.x - vp * csv.y)
                                   : (vp * csv.y + v * csv.x);
          Cp[(row + r) * ldc + col] = f2bf(o * fs);
        }
      } else if (OUT_BF16) {
        unsigned short* Cp = (unsigned short*)C;
#pragma unroll
        for (int r = 0; r < 4; ++r) Cp[(row + r) * ldc + col] = f2bf(acc[mf][nf][r]);
      } else {
        float* Cp = (float*)C;
#pragma unroll
        for (int r = 0; r < 4; ++r) Cp[(row + r) * ldc + col] = acc[mf][nf][r];
      }
    }
}

// ---------------- 128x256 8-phase GEMM body; optional fused-transpose (V -> vt) ----------------
template <bool OUT_BF16, bool VT_OUT>
__device__ __forceinline__ void gemm128_body(const unsigned short* __restrict__ A,
                                             const unsigned short* __restrict__ B,
                                             void* __restrict__ C,
                                             int M, int N, int K, int ldc,
                                             char* smem, int bm, int bn) {
  const int tid = threadIdx.x;
  const int lane = tid & 63, wid = tid >> 6;
  const int wr = wid >> 2, wc = wid & 3;
  const int l15 = lane & 15, l4 = lane >> 4;

  const int nk = K >> 6;

  unsigned short* AlB = (unsigned short*)smem;          // 2 x 8192 elems (32 KiB)
  unsigned short* BlB = (unsigned short*)smem + 16384;  // 2 x 16384 elems (64 KiB)

  const int srow = tid >> 3;
  const int scol = ((tid & 7) ^ (srow & 7)) * 8;
  const unsigned short* Asrc = A + (size_t)(bm * 128 + srow) * K + scol;
  const unsigned short* Bsrc = B + (size_t)(bn * 256 + srow) * K + scol;
  const int ldsdst = wid * 512;

#define STA2(b, kt, q) gl_lds16(Asrc + ((size_t)(q) * 64) * K + (kt) * 64, AlB + (b) * 8192 + (q) * 4096 + ldsdst)
#define STB2(b, kt, q) gl_lds16(Bsrc + ((size_t)(q) * 64) * K + (kt) * 64, BlB + (b) * 16384 + (q) * 4096 + ldsdst)

  const int swz = (l15 & 7) << 4;

  f32x4 acc[4][4] = {};
  bf16x8 Ax[2][2], Ay[2][2], B0f[2][2], B1f[2][2];

  STA2(0, 0, 0); STA2(0, 0, 1);
#pragma unroll
  for (int q = 0; q < 4; ++q) STB2(0, 0, q);
  {
    const int k1 = (nk > 1) ? 1 : 0;
    STA2(1, k1, 0); STA2(1, k1, 1);
    STB2(1, k1, 0); STB2(1, k1, 1);
  }
  wait_vmcnt4();
  phase_barrier();
  read_a2(Ax, (const char*)AlB, 0, wr, l15, l4, swz);
  read_b2(B0f, (const char*)BlB, 0, wc, l15, l4, swz);

#define HALF2(bb, AC, AA, t)                                               \
  {                                                                        \
    const int kt1 = ((t) + 1 < nk) ? (t) + 1 : nk - 1;                     \
    const int kt2 = ((t) + 2 < nk) ? (t) + 2 : nk - 1;                     \
    const char* Ab = (const char*)(AlB + (bb) * 8192);                     \
    const char* Bb = (const char*)(BlB + (bb) * 16384);                    \
    const char* Abn = (const char*)(AlB + ((bb) ^ 1) * 8192);              \
    const char* Bbn = (const char*)(BlB + ((bb) ^ 1) * 16384);             \
    STB2((bb) ^ 1, kt1, 2); STB2((bb) ^ 1, kt1, 3); /* finish t+1 */       \
    phase_barrier();                                                       \
    mfma_quad2(acc, AC, B0f, 0, 0); /* Q1 */                               \
    read_a2(AA, Ab, 1, wr, l15, l4, swz);                                  \
    STA2(bb, kt2, 0); STA2(bb, kt2, 1);                                    \
    phase_barrier();                                                       \
    mfma_quad2(acc, AA, B0f, 2, 0); /* Q2 */                               \
    read_b2(B1f, Bb, 1, wc, l15, l4, swz);                                 \
    STB2(bb, kt2, 0); STB2(bb, kt2, 1);                                    \
    phase_barrier();                                                       \
    mfma_quad2(acc, AA, B1f, 2, 2); /* Q3 */                               \
    wait_vmcnt4();                                                         \
    phase_barrier();                                                       \
    mfma_quad2(acc, AC, B1f, 0, 2); /* Q4 */                               \
    read_a2(AA, Abn, 0, wr, l15, l4, swz);                                 \
    read_b2(B0f, Bbn, 0, wc, l15, l4, swz);                                \
  }

  for (int t = 0; t < nk; t += 2) {
    HALF2(0, Ax, Ay, t);
    HALF2(1, Ay, Ax, t + 1);
  }
#undef HALF2
#undef STA2
#undef STB2

  __builtin_amdgcn_sched_barrier(0);
  asm volatile("s_waitcnt vmcnt(0)" ::: "memory");

  if (VT_OUT) {
    unsigned short* Tw = (unsigned short*)smem + (size_t)wid * 4672;  // 64*73 elems
#pragma unroll
    for (int mf = 0; mf < 4; ++mf)
#pragma unroll
      for (int nf = 0; nf < 4; ++nf)
#pragma unroll
        for (int r = 0; r < 4; ++r) {
          int lr = mf * 16 + l4 * 4 + r;   // local s
          int lc = nf * 16 + l15;          // local d
          Tw[lr * 73 + lc] = f2bf(acc[mf][nf][r]);
        }
    __syncthreads();
    unsigned short* vtp = (unsigned short*)C;
    const int gcol0 = bn * 256 + wc * 64;  // global d base (h*128+d)
    const int grow0 = bm * 128 + wr * 64;  // global s base
    const int dl8 = lane >> 3, sc = lane & 7;
#pragma unroll
    for (int it = 0; it < 8; ++it) {
      int dl = it * 8 + dl8;
      unsigned short tmp[8];
#pragma unroll
      for (int j = 0; j < 8; ++j) tmp[j] = Tw[(sc * 8 + j) * 73 + dl];
      unsigned short* dst = vtp + (size_t)(gcol0 + dl) * S_LEN + grow0 + sc * 8;
      *(ushort4*)dst = make_ushort4(tmp[0], tmp[1], tmp[2], tmp[3]);
      *(ushort4*)(dst + 4) = make_ushort4(tmp[4], tmp[5], tmp[6], tmp[7]);
    }
    return;
  }

  const size_t crow0 = (size_t)bm * 128 + wr * 64 + l4 * 4;
  const int ccol0 = bn * 256 + wc * 64 + l15;
#pragma unroll
  for (int mf = 0; mf < 4; ++mf)
#pragma unroll
    for (int nf = 0; nf < 4; ++nf) {
      size_t row = crow0 + mf * 16;
      int col = ccol0 + nf * 16;
      if (OUT_BF16) {
        unsigned short* Cp = (unsigned short*)C;
#pragma unroll
        for (int r = 0; r < 4; ++r) Cp[(row + r) * ldc + col] = f2bf(acc[mf][nf][r]);
      } else {
        float* Cp = (float*)C;
#pragma unroll
        for (int r = 0; r < 4; ++r) Cp[(row + r) * ldc + col] = acc[mf][nf][r];
      }
    }
}

// ---------------- merged QKV projection: blocks 0-255 QK+RoPE (bm-fastest), 256-511 V->vt ----------------
__global__ __launch_bounds__(512, 2) void qkv_proj(const unsigned short* __restrict__ xb,
                                                   const unsigned short* __restrict__ wqkvb,
                                                   unsigned short* __restrict__ qkvb,
                                                   unsigned short* __restrict__ vt,
                                                   const float* __restrict__ cs) {
  __shared__ __align__(16) char smem[131072];
  const int b = blockIdx.x;
  if (b < 256) {
    // bm-fastest: XCD k (= b%8 heuristic) keeps A-panel (2 MB) L2-resident
    const int bm = b & 7, bn = b >> 3;
    gemm256_body<true, true>(xb, wqkvb, qkvb, 2048, 8192, 4096, QKV_LD, smem, bm, bn, cs);
  } else {
    const int b2 = b - 256;
    gemm128_body<true, true>(xb, wqkvb + 33554432, vt, 2048, 4096, 4096, 0, smem,
                             b2 >> 4, b2 & 15);
  }
}

// ---------------- out projection (fp32 out), bm-fastest L2 affinity ----------------
__global__ __launch_bounds__(512, 2) void out_proj(const unsigned short* __restrict__ A,
                                                   const unsigned short* __restrict__ B,
                                                   float* __restrict__ C) {
  __shared__ __align__(16) char smem[98304];
  const int b = blockIdx.x;
  gemm128_body<false, false>(A, B, C, 2048, 4096, 4096, 4096, smem, b & 15, b >> 4);
}

// ---------------- flash attention split-K + hidden wo cast ----------------
__global__ __launch_bounds__(256) void attn_kernel(const unsigned short* __restrict__ qkv,
                                                   const unsigned short* __restrict__ vt,
                                                   float* __restrict__ pacc,
                                                   float* __restrict__ pm,
                                                   float* __restrict__ pl,
                                                   unsigned short* __restrict__ out,
                                                   const float* __restrict__ wo,
                                                   unsigned short* __restrict__ wob) {
  __shared__ __align__(16) unsigned short Klds[64 * 128];    // 16 KiB
  __shared__ __align__(16) unsigned short Vtlds[128 * 64];   // 16 KiB
  __shared__ __align__(16) unsigned short Plds[4][16 * 64];  // 8 KiB, XOR-swizzled
  const int tid = threadIdx.x, lane = tid & 63, w = tid >> 6;
  const int l15 = lane & 15, l4 = lane >> 4;
  const int h = blockIdx.x & 31;
  const int jj = blockIdx.x >> 5;

  // hidden wo cast: rides under attn's latency-bound phases; consumed 2 kernels later.
  {
    const int NT = 1536 * 256;
    for (int i = blockIdx.x * 256 + tid; i < 4194304; i += NT) cvt4(wo, wob, i);
  }

  int bq, c, kt0, kt1;
  if (jj < 17) {
    bq = 31 - jj; c = 0; kt0 = 0; kt1 = 16;
  } else {
    int k = jj - 17;
    if (k == 0)      { bq = 31;            c = 1; }
    else if (k & 1)  { bq = 30 - (k >> 1); c = 1; }
    else             { bq = 15 - (k >> 1); c = 0; }
    kt0 = c ? 16 : 0;
    kt1 = bq + 1;
  }
  if (jj == 16) kt1 = 16;  // bq=15: complete 16-tile job
  const int qw = bq * 64 + w * 16;

  bf16x8 qf[4];
#pragma unroll
  for (int ds = 0; ds < 4; ++ds)
    qf[ds] = *(const bf16x8*)&qkv[(size_t)(qw + l15) * QKV_LD + h * HDIM + ds * 32 + l4 * 8];

  f32x4 acc[8] = {};
  float m_run[4], l_run[4];
#pragma unroll
  for (int r = 0; r < 4; ++r) { m_run[r] = -1e30f; l_run[r] = 0.f; }

  for (int kt = kt0; kt < kt1; ++kt) {
    const int kv0 = kt * 64;
    __syncthreads();
#pragma unroll
    for (int i = 0; i < 4; ++i) {
      int b = (w * 4 + i) * 64 + lane;
      int r = b >> 4, cc = b & 15;
      gl_lds16(qkv + (size_t)(kv0 + r) * QKV_LD + 4096 + h * HDIM + ((cc ^ (r & 15)) * 8),
               &Klds[(w * 4 + i) * 512]);
    }
#pragma unroll
    for (int i = 0; i < 4; ++i) {
      int b = (w * 4 + i) * 64 + lane;
      int r = b >> 3, cc = b & 7;
      gl_lds16(vt + (size_t)(h * HDIM + r) * S_LEN + kv0 + ((cc ^ (r & 7)) * 8),
               &Vtlds[(w * 4 + i) * 512]);
    }
    __syncthreads();

    f32x4 s[4] = {};
    __builtin_amdgcn_s_setprio(1);
#pragma unroll
    for (int jt = 0; jt < 4; ++jt) {
      int kr = jt * 16 + l15;
#pragma unroll
      for (int ds = 0; ds < 4; ++ds) {
        int cc = (ds * 4 + l4) ^ (kr & 15);
        bf16x8 kf = *(const bf16x8*)&Klds[kr * 128 + cc * 8];
        s[jt] = __builtin_amdgcn_mfma_f32_16x16x32_bf16(qf[ds], kf, s[jt], 0, 0, 0);
      }
    }
    __builtin_amdgcn_s_setprio(0);

    const bool diag = (kt == bq);
    if (diag) {
#pragma unroll
      for (int jt = 0; jt < 4; ++jt)
#pragma unroll
        for (int r = 0; r < 4; ++r) {
          int kvg = kv0 + jt * 16 + l15;
          int qg = qw + l4 * 4 + r;
          if (kvg > qg) s[jt][r] = -1e30f;
        }
    }

    float alpha[4];
#pragma unroll
    for (int r = 0; r < 4; ++r) {
      float mx = fmaxf(fmaxf(s[0][r], s[1][r]), fmaxf(s[2][r], s[3][r]));
#pragma unroll
      for (int off = 1; off < 16; off <<= 1) mx = fmaxf(mx, __shfl_xor(mx, off, 64));
      float mi = fmaxf(m_run[r], mx);
      alpha[r] = exp2f(m_run[r] - mi);
      m_run[r] = mi;
      float sum = 0.f;
#pragma unroll
      for (int jt = 0; jt < 4; ++jt) {
        float p = exp2f(s[jt][r] - mi);
        s[jt][r] = p;
        sum += p;
      }
#pragma unroll
      for (int off = 1; off < 16; off <<= 1) sum += __shfl_xor(sum, off, 64);
      l_run[r] = l_run[r] * alpha[r] + sum;
    }
#pragma unroll
    for (int dt = 0; dt < 8; ++dt)
#pragma unroll
      for (int r = 0; r < 4; ++r) acc[dt][r] *= alpha[r];

    unsigned short* P = &Plds[w][0];
#pragma unroll
    for (int jt = 0; jt < 4; ++jt)
#pragma unroll
      for (int r = 0; r < 4; ++r) {
        int row = l4 * 4 + r, col = jt * 16 + l15;
        P[(row * 64 + col) ^ ((row & 7) << 3)] = f2bf(s[jt][r]);
      }

    __builtin_amdgcn_s_setprio(1);
#pragma unroll
    for (int ks = 0; ks < 2; ++ks) {
      bf16x8 pa = *(const bf16x8*)&P[(l15 * 64 + ks * 32 + l4 * 8) ^ ((l15 & 7) << 3)];
#pragma unroll
      for (int dt = 0; dt < 8; ++dt) {
        int vr = dt * 16 + l15;
        int cc = (ks * 4 + l4) ^ (vr & 7);
        bf16x8 vf = *(const bf16x8*)&Vtlds[vr * 64 + cc * 8];
        acc[dt] = __builtin_amdgcn_mfma_f32_16x16x32_bf16(pa, vf, acc[dt], 0, 0, 0);
      }
    }
    __builtin_amdgcn_s_setprio(0);
  }

  if (bq < 16) {
    float inv[4];
#pragma unroll
    for (int r = 0; r < 4; ++r) inv[r] = 1.f / l_run[r];
#pragma unroll
    for (int dt = 0; dt < 8; ++dt)
#pragma unroll
      for (int r = 0; r < 4; ++r) {
        int row = qw + l4 * 4 + r;
        int col = h * HDIM + dt * 16 + l15;
        out[(size_t)row * DMODEL + col] = f2bf(acc[dt][r] * inv[r]);
      }
  } else {
    const size_t bj = ((size_t)h * 32 + bq) * 2 + c;
    float* pa = pacc + bj * 8192 + (size_t)(w * 16) * 128;
#pragma unroll
    for (int dt = 0; dt < 8; ++dt)
#pragma unroll
      for (int r = 0; r < 4; ++r)
        pa[(l4 * 4 + r) * 128 + dt * 16 + l15] = acc[dt][r];
    if (l15 == 0) {
#pragma unroll
      for (int r = 0; r < 4; ++r) {
        pm[bj * 64 + w * 16 + l4 * 4 + r] = m_run[r];
        pl[bj * 64 + w * 16 + l4 * 4 + r] = l_run[r];
      }
    }
  }
}

// ---------------- combine partials (bq>=16 only) -> bf16 attn output ----------------
__global__ __launch_bounds__(256) void attn_combine(const float* __restrict__ pacc,
                                                    const float* __restrict__ pm,
                                                    const float* __restrict__ pl,
                                                    unsigned short* __restrict__ out) {
  const int x = blockIdx.x;
  const int bq = 16 + (x >> 5), h = x & 31;
  const int tid = threadIdx.x;
  const int row = tid >> 2;
  const int d0 = (tid & 3) * 32;
  const size_t base = ((size_t)h * 32 + bq) * 2;
  const float m0 = pm[base * 64 + row];
  const float l0 = pl[base * 64 + row];
  float m1 = pm[(base + 1) * 64 + row];
  float l1 = pl[(base + 1) * 64 + row];
  float M = fmaxf(m0, m1);
  float w0 = exp2f(m0 - M);
  float w1 = exp2f(m1 - M);
  float denom = w0 * l0 + w1 * l1;
  const float inv = 1.f / denom;
  const float* a0 = pacc + base * 8192 + row * 128 + d0;
  const float* a1 = a0 + 8192;
  unsigned short* op = out + (size_t)(bq * 64 + row) * DMODEL + h * HDIM + d0;
#pragma unroll
  for (int i = 0; i < 8; ++i) {
    float4 v = *(const float4*)(a0 + i * 4);
    float4 u = *(const float4*)(a1 + i * 4);
    ushort4 o;
    o.x = f2bf((w0 * v.x + w1 * u.x) * inv);
    o.y = f2bf((w0 * v.y + w1 * u.y) * inv);
    o.z = f2bf((w0 * v.z + w1 * u.z) * inv);
    o.w = f2bf((w0 * v.w + w1 * u.w) * inv);
    *(ushort4*)(op + i * 4) = o;
  }
}

// ---------------- launcher ----------------
extern "C" void kernel_launch(void* const* d_in, const int* in_sizes, int n_in,
                              void* d_out, int out_size, void* d_ws, size_t ws_size,
                              hipStream_t stream) {
  const float* x = (const float*)d_in[0];
  const float* fr = (const float*)d_in[1];
  const float* wq = (const float*)d_in[2];
  const float* wk = (const float*)d_in[3];
  const float* wv = (const float*)d_in[4];
  const float* wo = (const float*)d_in[5];

  char* ws = (char*)d_ws;
  const size_t OFF_XB   = 0;                       // 2048*4096*2      = 16 MB
  const size_t OFF_WQKV = 16777216;                // 12288*4096*2     = 96 MB
  const size_t OFF_WO   = OFF_WQKV + 100663296;    // 4096*4096*2      = 32 MB
  const size_t OFF_QKV  = OFF_WO + 33554432;       // 2048*12288*2     = 48 MB
  const size_t OFF_CS   = OFF_QKV + 50331648;      // 2048*128*4       = 1 MB
  const size_t OFF_VT   = OFF_CS + 1048576;        // 32*128*2048*2    = 16 MB
  const size_t OFF_ATTN = OFF_VT + 16777216;       // 2048*4096*2      = 16 MB

  unsigned short* xb    = (unsigned short*)(ws + OFF_XB);
  unsigned short* wqkvb = (unsigned short*)(ws + OFF_WQKV);
  unsigned short* wob   = (unsigned short*)(ws + OFF_WO);
  unsigned short* qkvb  = (unsigned short*)(ws + OFF_QKV);
  float*          cs    = (float*)(ws + OFF_CS);
  unsigned short* vt    = (unsigned short*)(ws + OFF_VT);
  unsigned short* attn  = (unsigned short*)(ws + OFF_ATTN);
  float* pacc = (float*)(ws + OFF_WQKV);
  float* pm   = (float*)(ws + OFF_WQKV + 67108864);
  float* pl   = (float*)(ws + OFF_WQKV + 67633152);

  // 1. merged prep: x/wq/wk/wv casts + rope table (wo cast deferred to attn)
  prep_inputs<<<2048, 256, 0, stream>>>(x, wq, wk, wv, fr, xb, wqkvb, cs);
  // 2. merged QKV projection: QK (RoPE+scale, bm-fastest) + V (fused transpose -> vt)
  qkv_proj<<<dim3(512), 512, 0, stream>>>(xb, wqkvb, qkvb, vt, cs);
  // 3. flash attention split-K (+hidden wo cast): 1536 blocks
  attn_kernel<<<dim3(1536), 256, 0, stream>>>(qkvb, vt, pacc, pm, pl, attn, wo, wob);
  // 3b. combine partials (bq>=16 only): 512 blocks
  attn_combine<<<dim3(512), 256, 0, stream>>>(pacc, pm, pl, attn);
  // 4. output projection: 128x256 8-phase (fp32 out, bm-fastest), grid = 256
  out_proj<<<dim3(256), 512, 0, stream>>>(attn, wob, (float*)d_out);
}

// Round 18
// 406.737 us; speedup vs baseline: 1.0049x; 1.0049x over previous
//
#include <hip/hip_runtime.h>
#include <hip/hip_bf16.h>
#include <stdint.h>

// B=1, S=2048, D=4096, H=32, HD=128
// Pipeline: prep(x/wq/wk/wv casts + rope table) -> qkv_proj (QK 256^2 w/ fused RoPE+scale,
//           V 128x256 w/ fused transpose -> vt) -> attn split-K (exp2 softmax, setprio,
//           + hidden wo cast) -> combine (bq>=16) -> out GEMM

typedef __attribute__((ext_vector_type(8))) short bf16x8;
typedef __attribute__((ext_vector_type(4))) float f32x4;

#define S_LEN 2048
#define DMODEL 4096
#define NHEAD 32
#define HDIM 128
#define QKV_LD 12288  // row stride of qk output buffer (Q 0..4095, K 4096..8191)

// Q pre-scale: 1/sqrt(128) * log2(e)  (folded so attn softmax uses native exp2)
#define QSCALE 0.1275247584969759f

// ---------------- helpers ----------------
__device__ __forceinline__ unsigned short f2bf(float f) {
  unsigned int u = __float_as_uint(f);
  unsigned int r = u + 0x7FFFu + ((u >> 16) & 1u);  // RNE
  return (unsigned short)(r >> 16);
}
__device__ __forceinline__ float bf2f(unsigned short h) {
  return __uint_as_float(((unsigned int)h) << 16);
}
__device__ __forceinline__ void gl_lds16(const void* g, void* l) {
  __builtin_amdgcn_global_load_lds((const __attribute__((address_space(1))) unsigned int*)g,
                                   (__attribute__((address_space(3))) unsigned int*)l, 16, 0, 0);
}
__device__ __forceinline__ void phase_barrier() {
  __builtin_amdgcn_sched_barrier(0);
  asm volatile("" ::: "memory");
  __builtin_amdgcn_s_barrier();
  asm volatile("" ::: "memory");
  __builtin_amdgcn_sched_barrier(0);
}
__device__ __forceinline__ void wait_vmcnt6() {
  __builtin_amdgcn_sched_barrier(0);
  asm volatile("s_waitcnt vmcnt(6)" ::: "memory");
  __builtin_amdgcn_sched_barrier(0);
}
__device__ __forceinline__ void wait_vmcnt4() {
  __builtin_amdgcn_sched_barrier(0);
  asm volatile("s_waitcnt vmcnt(4)" ::: "memory");
  __builtin_amdgcn_sched_barrier(0);
}

// ---------------- merged prep: x/wq/wk/wv casts + rope cos/sin table ----------------
__device__ __forceinline__ void cvt4(const float* __restrict__ s, unsigned short* __restrict__ d,
                                     int i) {
  float4 v = ((const float4*)s)[i];
  ushort4 o;
  o.x = f2bf(v.x); o.y = f2bf(v.y); o.z = f2bf(v.z); o.w = f2bf(v.w);
  ((ushort4*)d)[i] = o;
}

__global__ __launch_bounds__(256) void prep_inputs(const float* __restrict__ x,
                                                   const float* __restrict__ wq,
                                                   const float* __restrict__ wk,
                                                   const float* __restrict__ wv,
                                                   const float* __restrict__ fr,
                                                   unsigned short* __restrict__ xb,
                                                   unsigned short* __restrict__ wqkvb,
                                                   float* __restrict__ cs) {
  const int NX = 2097152;   // x float4 count
  const int NW = 4194304;   // each weight float4 count
  const int NR = S_LEN * 64;
  const int total = NX + 3 * NW + NR;
  int i = blockIdx.x * blockDim.x + threadIdx.x;
  int stride = gridDim.x * blockDim.x;
  for (; i < total; i += stride) {
    if (i < NX) {
      cvt4(x, xb, i);
    } else if (i < NX + NW) {
      cvt4(wq, wqkvb, i - NX);
    } else if (i < NX + 2 * NW) {
      cvt4(wk, wqkvb + 16777216, i - NX - NW);
    } else if (i < NX + 3 * NW) {
      cvt4(wv, wqkvb + 33554432, i - NX - 2 * NW);
    } else {
      int j = i - (NX + 3 * NW);
      float f = fr[j];
      cs[2 * j]     = cosf(f);
      cs[2 * j + 1] = sinf(f);
    }
  }
}

// ---------------- shared GEMM building blocks ----------------
__device__ __forceinline__ void mfma_quad(f32x4 (&acc)[8][4], const bf16x8 (&af)[4][2],
                                          const bf16x8 (&bf)[2][2], int moff, int noff) {
  __builtin_amdgcn_s_setprio(1);
#pragma unroll
  for (int mi = 0; mi < 4; ++mi)
#pragma unroll
    for (int ni = 0; ni < 2; ++ni)
#pragma unroll
      for (int kk = 0; kk < 2; ++kk)
        acc[moff + mi][noff + ni] = __builtin_amdgcn_mfma_f32_16x16x32_bf16(
            af[mi][kk], bf[ni][kk], acc[moff + mi][noff + ni], 0, 0, 0);
  __builtin_amdgcn_s_setprio(0);
}
__device__ __forceinline__ void mfma_quad2(f32x4 (&acc)[4][4], const bf16x8 (&af)[2][2],
                                           const bf16x8 (&bf)[2][2], int moff, int noff) {
  __builtin_amdgcn_s_setprio(1);
#pragma unroll
  for (int mi = 0; mi < 2; ++mi)
#pragma unroll
    for (int ni = 0; ni < 2; ++ni)
#pragma unroll
      for (int kk = 0; kk < 2; ++kk)
        acc[moff + mi][noff + ni] = __builtin_amdgcn_mfma_f32_16x16x32_bf16(
            af[mi][kk], bf[ni][kk], acc[moff + mi][noff + ni], 0, 0, 0);
  __builtin_amdgcn_s_setprio(0);
}

__device__ __forceinline__ void read_a(bf16x8 (&dst)[4][2], const char* base, int half,
                                       int wr, int l15, int l4, int swz) {
#pragma unroll
  for (int mi = 0; mi < 4; ++mi) {
    const char* rb = base + (wr * 128 + half * 64 + mi * 16 + l15) * 128;
#pragma unroll
    for (int kk = 0; kk < 2; ++kk)
      dst[mi][kk] = *(const bf16x8*)(rb + ((kk * 64 + l4 * 16) ^ swz));
  }
}
__device__ __forceinline__ void read_b(bf16x8 (&dst)[2][2], const char* base, int half,
                                       int wc, int l15, int l4, int swz) {
#pragma unroll
  for (int ni = 0; ni < 2; ++ni) {
    const char* rb = base + (wc * 64 + half * 32 + ni * 16 + l15) * 128;
#pragma unroll
    for (int kk = 0; kk < 2; ++kk)
      dst[ni][kk] = *(const bf16x8*)(rb + ((kk * 64 + l4 * 16) ^ swz));
  }
}
__device__ __forceinline__ void read_a2(bf16x8 (&dst)[2][2], const char* base, int half,
                                        int wr, int l15, int l4, int swz) {
#pragma unroll
  for (int mi = 0; mi < 2; ++mi) {
    const char* rb = base + (wr * 64 + half * 32 + mi * 16 + l15) * 128;
#pragma unroll
    for (int kk = 0; kk < 2; ++kk)
      dst[mi][kk] = *(const bf16x8*)(rb + ((kk * 64 + l4 * 16) ^ swz));
  }
}
__device__ __forceinline__ void read_b2(bf16x8 (&dst)[2][2], const char* base, int half,
                                        int wc, int l15, int l4, int swz) {
#pragma unroll
  for (int ni = 0; ni < 2; ++ni) {
    const char* rb = base + (wc * 64 + half * 32 + ni * 16 + l15) * 128;
#pragma unroll
    for (int kk = 0; kk < 2; ++kk)
      dst[ni][kk] = *(const bf16x8*)(rb + ((kk * 64 + l4 * 16) ^ swz));
  }
}

// ---------------- 256^2 8-phase GEMM body, register-pipelined; fused RoPE + Q-scale ----------------
template <bool OUT_BF16, bool ROPE>
__device__ __forceinline__ void gemm256_body(const unsigned short* __restrict__ A,
                                             const unsigned short* __restrict__ B,
                                             void* __restrict__ C,
                                             int M, int N, int K, int ldc,
                                             char* smem, int wg,
                                             const float* __restrict__ cs) {
  const int tid = threadIdx.x;
  const int lane = tid & 63, wid = tid >> 6;
  const int wr = wid >> 2, wc = wid & 3;
  const int l15 = lane & 15, l4 = lane >> 4;

  const int nbn = N >> 8;
  const int bm = wg / nbn, bn = wg % nbn;
  const int nk = K >> 6;

  unsigned short* AlB = (unsigned short*)smem;          // 2 x 16384 elems (64 KiB)
  unsigned short* BlB = (unsigned short*)smem + 32768;  // 2 x 16384 elems (64 KiB)

  const int srow = tid >> 3;
  const int scol = ((tid & 7) ^ (srow & 7)) * 8;
  const unsigned short* Asrc = A + (size_t)(bm * 256 + srow) * K + scol;
  const unsigned short* Bsrc = B + (size_t)(bn * 256 + srow) * K + scol;
  const int ldsdst = wid * 512;

#define STA(b, kt, q) gl_lds16(Asrc + ((size_t)(q) * 64) * K + (kt) * 64, AlB + (b) * 16384 + (q) * 4096 + ldsdst)
#define STB(b, kt, q) gl_lds16(Bsrc + ((size_t)(q) * 64) * K + (kt) * 64, BlB + (b) * 16384 + (q) * 4096 + ldsdst)

  const int swz = (l15 & 7) << 4;

  f32x4 acc[8][4] = {};
  bf16x8 Ax[4][2], Ay[4][2], B0f[2][2], B1f[2][2];

#pragma unroll
  for (int q = 0; q < 4; ++q) STA(0, 0, q);
#pragma unroll
  for (int q = 0; q < 4; ++q) STB(0, 0, q);
  {
    const int k1 = (nk > 1) ? 1 : 0;
    STA(1, k1, 0); STA(1, k1, 2);
    STB(1, k1, 0); STB(1, k1, 1); STB(1, k1, 2); STB(1, k1, 3);
  }
  wait_vmcnt6();
  phase_barrier();
  read_a(Ax, (const char*)AlB, 0, wr, l15, l4, swz);
  read_b(B0f, (const char*)BlB, 0, wc, l15, l4, swz);

#define HALF(bb, AC, AA, t)                                                \
  {                                                                        \
    const int kt1 = ((t) + 1 < nk) ? (t) + 1 : nk - 1;                     \
    const int kt2 = ((t) + 2 < nk) ? (t) + 2 : nk - 1;                     \
    const char* Ab = (const char*)(AlB + (bb) * 16384);                    \
    const char* Bb = (const char*)(BlB + (bb) * 16384);                    \
    const char* Abn = (const char*)(AlB + ((bb) ^ 1) * 16384);             \
    const char* Bbn = (const char*)(BlB + ((bb) ^ 1) * 16384);             \
    STA((bb) ^ 1, kt1, 1); STA((bb) ^ 1, kt1, 3);                          \
    phase_barrier();                                                       \
    mfma_quad(acc, AC, B0f, 0, 0); /* Q1 */                                \
    read_a(AA, Ab, 1, wr, l15, l4, swz);                                   \
    STA(bb, kt2, 0); STA(bb, kt2, 2);                                      \
    phase_barrier();                                                       \
    mfma_quad(acc, AA, B0f, 4, 0); /* Q2 */                                \
    read_b(B1f, Bb, 1, wc, l15, l4, swz);                                  \
    STB(bb, kt2, 0); STB(bb, kt2, 1);                                      \
    phase_barrier();                                                       \
    mfma_quad(acc, AA, B1f, 4, 2); /* Q3 */                                \
    STB(bb, kt2, 2); STB(bb, kt2, 3);                                      \
    wait_vmcnt6();                                                         \
    phase_barrier();                                                       \
    mfma_quad(acc, AC, B1f, 0, 2); /* Q4 */                                \
    read_a(AA, Abn, 0, wr, l15, l4, swz);                                  \
    read_b(B0f, Bbn, 0, wc, l15, l4, swz);                                 \
  }

  for (int t = 0; t < nk; t += 2) {
    HALF(0, Ax, Ay, t);
    HALF(1, Ay, Ax, t + 1);
  }
#undef HALF
#undef STA
#undef STB

  __builtin_amdgcn_sched_barrier(0);
  asm volatile("s_waitcnt vmcnt(0)" ::: "memory");

  const size_t crow0 = (size_t)bm * 256 + wr * 128 + l4 * 4;
  const int ccol0 = bn * 256 + wc * 64 + l15;
#pragma unroll
  for (int mf = 0; mf < 8; ++mf)
#pragma unroll
    for (int nf = 0; nf < 4; ++nf) {
      size_t row = crow0 + mf * 16;
      int col = ccol0 + nf * 16;
      if (ROPE) {
        const int d = col & (HDIM - 1);
        const int i2 = d & ~1;
        const float fs = (col < 4096) ? QSCALE : 1.0f;
        unsigned short* Cp = (unsigned short*)C;
#pragma unroll
        for (int r = 0; r < 4; ++r) {
          float v = acc[mf][nf][r];
          float vp = __shfl_xor(v, 1, 64);
          float2 csv = *(const float2*)&cs[(row + r) * HDIM + i2];
          float o = ((d & 1) == 0) ? (v * csv.x - vp * csv.y)
                                   : (vp * csv.y + v * csv.x);
          Cp[(row + r) * ldc + col] = f2bf(o * fs);
        }
      } else if (OUT_BF16) {
        unsigned short* Cp = (unsigned short*)C;
#pragma unroll
        for (int r = 0; r < 4; ++r) Cp[(row + r) * ldc + col] = f2bf(acc[mf][nf][r]);
      } else {
        float* Cp = (float*)C;
#pragma unroll
        for (int r = 0; r < 4; ++r) Cp[(row + r) * ldc + col] = acc[mf][nf][r];
      }
    }
}

// ---------------- 128x256 8-phase GEMM body; optional fused-transpose (V -> vt) ----------------
template <bool OUT_BF16, bool VT_OUT>
__device__ __forceinline__ void gemm128_body(const unsigned short* __restrict__ A,
                                             const unsigned short* __restrict__ B,
                                             void* __restrict__ C,
                                             int M, int N, int K, int ldc,
                                             char* smem, int wg) {
  const int tid = threadIdx.x;
  const int lane = tid & 63, wid = tid >> 6;
  const int wr = wid >> 2, wc = wid & 3;
  const int l15 = lane & 15, l4 = lane >> 4;

  const int nbn = N >> 8;
  const int bm = wg / nbn, bn = wg % nbn;
  const int nk = K >> 6;

  unsigned short* AlB = (unsigned short*)smem;          // 2 x 8192 elems (32 KiB)
  unsigned short* BlB = (unsigned short*)smem + 16384;  // 2 x 16384 elems (64 KiB)

  const int srow = tid >> 3;
  const int scol = ((tid & 7) ^ (srow & 7)) * 8;
  const unsigned short* Asrc = A + (size_t)(bm * 128 + srow) * K + scol;
  const unsigned short* Bsrc = B + (size_t)(bn * 256 + srow) * K + scol;
  const int ldsdst = wid * 512;

#define STA2(b, kt, q) gl_lds16(Asrc + ((size_t)(q) * 64) * K + (kt) * 64, AlB + (b) * 8192 + (q) * 4096 + ldsdst)
#define STB2(b, kt, q) gl_lds16(Bsrc + ((size_t)(q) * 64) * K + (kt) * 64, BlB + (b) * 16384 + (q) * 4096 + ldsdst)

  const int swz = (l15 & 7) << 4;

  f32x4 acc[4][4] = {};
  bf16x8 Ax[2][2], Ay[2][2], B0f[2][2], B1f[2][2];

  STA2(0, 0, 0); STA2(0, 0, 1);
#pragma unroll
  for (int q = 0; q < 4; ++q) STB2(0, 0, q);
  {
    const int k1 = (nk > 1) ? 1 : 0;
    STA2(1, k1, 0); STA2(1, k1, 1);
    STB2(1, k1, 0); STB2(1, k1, 1);
  }
  wait_vmcnt4();
  phase_barrier();
  read_a2(Ax, (const char*)AlB, 0, wr, l15, l4, swz);
  read_b2(B0f, (const char*)BlB, 0, wc, l15, l4, swz);

#define HALF2(bb, AC, AA, t)                                               \
  {                                                                        \
    const int kt1 = ((t) + 1 < nk) ? (t) + 1 : nk - 1;                     \
    const int kt2 = ((t) + 2 < nk) ? (t) + 2 : nk - 1;                     \
    const char* Ab = (const char*)(AlB + (bb) * 8192);                     \
    const char* Bb = (const char*)(BlB + (bb) * 16384);                    \
    const char* Abn = (const char*)(AlB + ((bb) ^ 1) * 8192);              \
    const char* Bbn = (const char*)(BlB + ((bb) ^ 1) * 16384);             \
    STB2((bb) ^ 1, kt1, 2); STB2((bb) ^ 1, kt1, 3); /* finish t+1 */       \
    phase_barrier();                                                       \
    mfma_quad2(acc, AC, B0f, 0, 0); /* Q1 */                               \
    read_a2(AA, Ab, 1, wr, l15, l4, swz);                                  \
    STA2(bb, kt2, 0); STA2(bb, kt2, 1);                                    \
    phase_barrier();                                                       \
    mfma_quad2(acc, AA, B0f, 2, 0); /* Q2 */                               \
    read_b2(B1f, Bb, 1, wc, l15, l4, swz);                                 \
    STB2(bb, kt2, 0); STB2(bb, kt2, 1);                                    \
    phase_barrier();                                                       \
    mfma_quad2(acc, AA, B1f, 2, 2); /* Q3 */                               \
    wait_vmcnt4();                                                         \
    phase_barrier();                                                       \
    mfma_quad2(acc, AC, B1f, 0, 2); /* Q4 */                               \
    read_a2(AA, Abn, 0, wr, l15, l4, swz);                                 \
    read_b2(B0f, Bbn, 0, wc, l15, l4, swz);                                \
  }

  for (int t = 0; t < nk; t += 2) {
    HALF2(0, Ax, Ay, t);
    HALF2(1, Ay, Ax, t + 1);
  }
#undef HALF2
#undef STA2
#undef STB2

  __builtin_amdgcn_sched_barrier(0);
  asm volatile("s_waitcnt vmcnt(0)" ::: "memory");

  if (VT_OUT) {
    unsigned short* Tw = (unsigned short*)smem + (size_t)wid * 4672;  // 64*73 elems
#pragma unroll
    for (int mf = 0; mf < 4; ++mf)
#pragma unroll
      for (int nf = 0; nf < 4; ++nf)
#pragma unroll
        for (int r = 0; r < 4; ++r) {
          int lr = mf * 16 + l4 * 4 + r;   // local s
          int lc = nf * 16 + l15;          // local d
          Tw[lr * 73 + lc] = f2bf(acc[mf][nf][r]);
        }
    __syncthreads();
    unsigned short* vtp = (unsigned short*)C;
    const int gcol0 = bn * 256 + wc * 64;  // global d base (h*128+d)
    const int grow0 = bm * 128 + wr * 64;  // global s base
    const int dl8 = lane >> 3, sc = lane & 7;
#pragma unroll
    for (int it = 0; it < 8; ++it) {
      int dl = it * 8 + dl8;
      unsigned short tmp[8];
#pragma unroll
      for (int j = 0; j < 8; ++j) tmp[j] = Tw[(sc * 8 + j) * 73 + dl];
      unsigned short* dst = vtp + (size_t)(gcol0 + dl) * S_LEN + grow0 + sc * 8;
      *(ushort4*)dst = make_ushort4(tmp[0], tmp[1], tmp[2], tmp[3]);
      *(ushort4*)(dst + 4) = make_ushort4(tmp[4], tmp[5], tmp[6], tmp[7]);
    }
    return;
  }

  const size_t crow0 = (size_t)bm * 128 + wr * 64 + l4 * 4;
  const int ccol0 = bn * 256 + wc * 64 + l15;
#pragma unroll
  for (int mf = 0; mf < 4; ++mf)
#pragma unroll
    for (int nf = 0; nf < 4; ++nf) {
      size_t row = crow0 + mf * 16;
      int col = ccol0 + nf * 16;
      if (OUT_BF16) {
        unsigned short* Cp = (unsigned short*)C;
#pragma unroll
        for (int r = 0; r < 4; ++r) Cp[(row + r) * ldc + col] = f2bf(acc[mf][nf][r]);
      } else {
        float* Cp = (float*)C;
#pragma unroll
        for (int r = 0; r < 4; ++r) Cp[(row + r) * ldc + col] = acc[mf][nf][r];
      }
    }
}

// ---------------- merged QKV projection: blocks 0-255 QK+RoPE (256^2), 256-511 V->vt ----------------
__global__ __launch_bounds__(512, 2) void qkv_proj(const unsigned short* __restrict__ xb,
                                                   const unsigned short* __restrict__ wqkvb,
                                                   unsigned short* __restrict__ qkvb,
                                                   unsigned short* __restrict__ vt,
                                                   const float* __restrict__ cs) {
  __shared__ __align__(16) char smem[131072];
  const int b = blockIdx.x;
  if (b < 256) {
    gemm256_body<true, true>(xb, wqkvb, qkvb, 2048, 8192, 4096, QKV_LD, smem, b, cs);
  } else {
    gemm128_body<true, true>(xb, wqkvb + 33554432, vt, 2048, 4096, 4096, 0, smem, b - 256);
  }
}

// ---------------- out projection (fp32 out) ----------------
__global__ __launch_bounds__(512, 2) void out_proj(const unsigned short* __restrict__ A,
                                                   const unsigned short* __restrict__ B,
                                                   float* __restrict__ C) {
  __shared__ __align__(16) char smem[98304];
  gemm128_body<false, false>(A, B, C, 2048, 4096, 4096, 4096, smem, blockIdx.x);
}

// ---------------- flash attention split-K + hidden wo cast ----------------
__global__ __launch_bounds__(256) void attn_kernel(const unsigned short* __restrict__ qkv,
                                                   const unsigned short* __restrict__ vt,
                                                   float* __restrict__ pacc,
                                                   float* __restrict__ pm,
                                                   float* __restrict__ pl,
                                                   unsigned short* __restrict__ out,
                                                   const float* __restrict__ wo,
                                                   unsigned short* __restrict__ wob) {
  __shared__ __align__(16) unsigned short Klds[64 * 128];    // 16 KiB
  __shared__ __align__(16) unsigned short Vtlds[128 * 64];   // 16 KiB
  __shared__ __align__(16) unsigned short Plds[4][16 * 64];  // 8 KiB, XOR-swizzled
  const int tid = threadIdx.x, lane = tid & 63, w = tid >> 6;
  const int l15 = lane & 15, l4 = lane >> 4;
  const int h = blockIdx.x & 31;
  const int jj = blockIdx.x >> 5;

  // hidden wo cast: rides under attn's latency-bound phases; consumed 2 kernels later.
  {
    const int NT = 1536 * 256;
    for (int i = blockIdx.x * 256 + tid; i < 4194304; i += NT) cvt4(wo, wob, i);
  }

  int bq, c, kt0, kt1;
  if (jj < 17) {
    bq = 31 - jj; c = 0; kt0 = 0; kt1 = 16;
  } else {
    int k = jj - 17;
    if (k == 0)      { bq = 31;            c = 1; }
    else if (k & 1)  { bq = 30 - (k >> 1); c = 1; }
    else             { bq = 15 - (k >> 1); c = 0; }
    kt0 = c ? 16 : 0;
    kt1 = bq + 1;
  }
  if (jj == 16) kt1 = 16;  // bq=15: complete 16-tile job
  const int qw = bq * 64 + w * 16;

  bf16x8 qf[4];
#pragma unroll
  for (int ds = 0; ds < 4; ++ds)
    qf[ds] = *(const bf16x8*)&qkv[(size_t)(qw + l15) * QKV_LD + h * HDIM + ds * 32 + l4 * 8];

  f32x4 acc[8] = {};
  float m_run[4], l_run[4];
#pragma unroll
  for (int r = 0; r < 4; ++r) { m_run[r] = -1e30f; l_run[r] = 0.f; }

  for (int kt = kt0; kt < kt1; ++kt) {
    const int kv0 = kt * 64;
    __syncthreads();
#pragma unroll
    for (int i = 0; i < 4; ++i) {
      int b = (w * 4 + i) * 64 + lane;
      int r = b >> 4, cc = b & 15;
      gl_lds16(qkv + (size_t)(kv0 + r) * QKV_LD + 4096 + h * HDIM + ((cc ^ (r & 15)) * 8),
               &Klds[(w * 4 + i) * 512]);
    }
#pragma unroll
    for (int i = 0; i < 4; ++i) {
      int b = (w * 4 + i) * 64 + lane;
      int r = b >> 3, cc = b & 7;
      gl_lds16(vt + (size_t)(h * HDIM + r) * S_LEN + kv0 + ((cc ^ (r & 7)) * 8),
               &Vtlds[(w * 4 + i) * 512]);
    }
    __syncthreads();

    f32x4 s[4] = {};
    __builtin_amdgcn_s_setprio(1);
#pragma unroll
    for (int jt = 0; jt < 4; ++jt) {
      int kr = jt * 16 + l15;
#pragma unroll
      for (int ds = 0; ds < 4; ++ds) {
        int cc = (ds * 4 + l4) ^ (kr & 15);
        bf16x8 kf = *(const bf16x8*)&Klds[kr * 128 + cc * 8];
        s[jt] = __builtin_amdgcn_mfma_f32_16x16x32_bf16(qf[ds], kf, s[jt], 0, 0, 0);
      }
    }
    __builtin_amdgcn_s_setprio(0);

    const bool diag = (kt == bq);
    if (diag) {
#pragma unroll
      for (int jt = 0; jt < 4; ++jt)
#pragma unroll
        for (int r = 0; r < 4; ++r) {
          int kvg = kv0 + jt * 16 + l15;
          int qg = qw + l4 * 4 + r;
          if (kvg > qg) s[jt][r] = -1e30f;
        }
    }

    float alpha[4];
#pragma unroll
    for (int r = 0; r < 4; ++r) {
      float mx = fmaxf(fmaxf(s[0][r], s[1][r]), fmaxf(s[2][r], s[3][r]));
#pragma unroll
      for (int off = 1; off < 16; off <<= 1) mx = fmaxf(mx, __shfl_xor(mx, off, 64));
      float mi = fmaxf(m_run[r], mx);
      alpha[r] = exp2f(m_run[r] - mi);
      m_run[r] = mi;
      float sum = 0.f;
#pragma unroll
      for (int jt = 0; jt < 4; ++jt) {
        float p = exp2f(s[jt][r] - mi);
        s[jt][r] = p;
        sum += p;
      }
#pragma unroll
      for (int off = 1; off < 16; off <<= 1) sum += __shfl_xor(sum, off, 64);
      l_run[r] = l_run[r] * alpha[r] + sum;
    }
#pragma unroll
    for (int dt = 0; dt < 8; ++dt)
#pragma unroll
      for (int r = 0; r < 4; ++r) acc[dt][r] *= alpha[r];

    unsigned short* P = &Plds[w][0];
#pragma unroll
    for (int jt = 0; jt < 4; ++jt)
#pragma unroll
      for (int r = 0; r < 4; ++r) {
        int row = l4 * 4 + r, col = jt * 16 + l15;
        P[(row * 64 + col) ^ ((row & 7) << 3)] = f2bf(s[jt][r]);
      }

    __builtin_amdgcn_s_setprio(1);
#pragma unroll
    for (int ks = 0; ks < 2; ++ks) {
      bf16x8 pa = *(const bf16x8*)&P[(l15 * 64 + ks * 32 + l4 * 8) ^ ((l15 & 7) << 3)];
#pragma unroll
      for (int dt = 0; dt < 8; ++dt) {
        int vr = dt * 16 + l15;
        int cc = (ks * 4 + l4) ^ (vr & 7);
        bf16x8 vf = *(const bf16x8*)&Vtlds[vr * 64 + cc * 8];
        acc[dt] = __builtin_amdgcn_mfma_f32_16x16x32_bf16(pa, vf, acc[dt], 0, 0, 0);
      }
    }
    __builtin_amdgcn_s_setprio(0);
  }

  if (bq < 16) {
    float inv[4];
#pragma unroll
    for (int r = 0; r < 4; ++r) inv[r] = 1.f / l_run[r];
#pragma unroll
    for (int dt = 0; dt < 8; ++dt)
#pragma unroll
      for (int r = 0; r < 4; ++r) {
        int row = qw + l4 * 4 + r;
        int col = h * HDIM + dt * 16 + l15;
        out[(size_t)row * DMODEL + col] = f2bf(acc[dt][r] * inv[r]);
      }
  } else {
    const size_t bj = ((size_t)h * 32 + bq) * 2 + c;
    float* pa = pacc + bj * 8192 + (size_t)(w * 16) * 128;
#pragma unroll
    for (int dt = 0; dt < 8; ++dt)
#pragma unroll
      for (int r = 0; r < 4; ++r)
        pa[(l4 * 4 + r) * 128 + dt * 16 + l15] = acc[dt][r];
    if (l15 == 0) {
#pragma unroll
      for (int r = 0; r < 4; ++r) {
        pm[bj * 64 + w * 16 + l4 * 4 + r] = m_run[r];
        pl[bj * 64 + w * 16 + l4 * 4 + r] = l_run[r];
      }
    }
  }
}

// ---------------- combine partials (bq>=16 only) -> bf16 attn output ----------------
__global__ __launch_bounds__(256) void attn_combine(const float* __restrict__ pacc,
                                                    const float* __restrict__ pm,
                                                    const float* __restrict__ pl,
                                                    unsigned short* __restrict__ out) {
  const int x = blockIdx.x;
  const int bq = 16 + (x >> 5), h = x & 31;
  const int tid = threadIdx.x;
  const int row = tid >> 2;
  const int d0 = (tid & 3) * 32;
  const size_t base = ((size_t)h * 32 + bq) * 2;
  const float m0 = pm[base * 64 + row];
  const float l0 = pl[base * 64 + row];
  float m1 = pm[(base + 1) * 64 + row];
  float l1 = pl[(base + 1) * 64 + row];
  float M = fmaxf(m0, m1);
  float w0 = exp2f(m0 - M);
  float w1 = exp2f(m1 - M);
  float denom = w0 * l0 + w1 * l1;
  const float inv = 1.f / denom;
  const float* a0 = pacc + base * 8192 + row * 128 + d0;
  const float* a1 = a0 + 8192;
  unsigned short* op = out + (size_t)(bq * 64 + row) * DMODEL + h * HDIM + d0;
#pragma unroll
  for (int i = 0; i < 8; ++i) {
    float4 v = *(const float4*)(a0 + i * 4);
    float4 u = *(const float4*)(a1 + i * 4);
    ushort4 o;
    o.x = f2bf((w0 * v.x + w1 * u.x) * inv);
    o.y = f2bf((w0 * v.y + w1 * u.y) * inv);
    o.z = f2bf((w0 * v.z + w1 * u.z) * inv);
    o.w = f2bf((w0 * v.w + w1 * u.w) * inv);
    *(ushort4*)(op + i * 4) = o;
  }
}

// ---------------- launcher ----------------
extern "C" void kernel_launch(void* const* d_in, const int* in_sizes, int n_in,
                              void* d_out, int out_size, void* d_ws, size_t ws_size,
                              hipStream_t stream) {
  const float* x = (const float*)d_in[0];
  const float* fr = (const float*)d_in[1];
  const float* wq = (const float*)d_in[2];
  const float* wk = (const float*)d_in[3];
  const float* wv = (const float*)d_in[4];
  const float* wo = (const float*)d_in[5];

  char* ws = (char*)d_ws;
  const size_t OFF_XB   = 0;                       // 2048*4096*2      = 16 MB
  const size_t OFF_WQKV = 16777216;                // 12288*4096*2     = 96 MB
  const size_t OFF_WO   = OFF_WQKV + 100663296;    // 4096*4096*2      = 32 MB
  const size_t OFF_QKV  = OFF_WO + 33554432;       // 2048*12288*2     = 48 MB
  const size_t OFF_CS   = OFF_QKV + 50331648;      // 2048*128*4       = 1 MB
  const size_t OFF_VT   = OFF_CS + 1048576;        // 32*128*2048*2    = 16 MB
  const size_t OFF_ATTN = OFF_VT + 16777216;       // 2048*4096*2      = 16 MB

  unsigned short* xb    = (unsigned short*)(ws + OFF_XB);
  unsigned short* wqkvb = (unsigned short*)(ws + OFF_WQKV);
  unsigned short* wob   = (unsigned short*)(ws + OFF_WO);
  unsigned short* qkvb  = (unsigned short*)(ws + OFF_QKV);
  float*          cs    = (float*)(ws + OFF_CS);
  unsigned short* vt    = (unsigned short*)(ws + OFF_VT);
  unsigned short* attn  = (unsigned short*)(ws + OFF_ATTN);
  float* pacc = (float*)(ws + OFF_WQKV);
  float* pm   = (float*)(ws + OFF_WQKV + 67108864);
  float* pl   = (float*)(ws + OFF_WQKV + 67633152);

  // 1. merged prep: x/wq/wk/wv casts + rope table (wo cast deferred to attn)
  prep_inputs<<<2048, 256, 0, stream>>>(x, wq, wk, wv, fr, xb, wqkvb, cs);
  // 2. merged QKV projection: QK (RoPE+scale epilogue) + V (fused transpose -> vt)
  qkv_proj<<<dim3(512), 512, 0, stream>>>(xb, wqkvb, qkvb, vt, cs);
  // 3. flash attention split-K (+hidden wo cast): 1536 blocks
  attn_kernel<<<dim3(1536), 256, 0, stream>>>(qkvb, vt, pacc, pm, pl, attn, wo, wob);
  // 3b. combine partials (bq>=16 only): 512 blocks
  attn_combine<<<dim3(512), 256, 0, stream>>>(pacc, pm, pl, attn);
  // 4. output projection: 128x256 8-phase (fp32 out), grid = 256 = exactly 1 round
  out_proj<<<dim3(256), 512, 0, stream>>>(attn, wob, (float*)d_out);
}